// Round 1
// baseline (486.557 us; speedup 1.0000x reference)
//
#include <hip/hip_runtime.h>

#define HW 36864      // 192*192
#define WD 192
#define BB 8
#define CC 10

// ---------------------------------------------------------------------------
// Kernel A: all 1x1 pointwise maps + h0 copy.
//  - decomp_map = w_dmap * [f1,h1,h2] + b  -> out region O1 (softmax done later)
//  - comp_map_u = sigmoid(w_cau * [p1..p4] + b) -> O2
//  - comp_map_l = sigmoid(w_cal * [p5,p6] + b)  -> O3
//  - xh_new[0] = h_nodes[0]
// ---------------------------------------------------------------------------
__global__ __launch_bounds__(256) void maps_kernel(
    const float* __restrict__ f_nodes, const float* __restrict__ h_nodes,
    const float* __restrict__ p_nodes,
    const float* __restrict__ w_dmap, const float* __restrict__ b_dmap,
    const float* __restrict__ w_cau, const float* __restrict__ b_cau,
    const float* __restrict__ w_cal, const float* __restrict__ b_cal,
    float* __restrict__ out)
{
    int px = blockIdx.x * 256 + threadIdx.x;   // [0, 8*36864)
    int b  = px / HW;
    int sp = px - b * HW;

    const float* f1 = f_nodes + (size_t)(1*BB + b)*CC*HW + sp;
    const float* h0 = h_nodes + (size_t)(0*BB + b)*CC*HW + sp;
    const float* h1 = h_nodes + (size_t)(1*BB + b)*CC*HW + sp;
    const float* h2 = h_nodes + (size_t)(2*BB + b)*CC*HW + sp;

    float fv[10], h1v[10], h2v[10];
    #pragma unroll
    for (int c = 0; c < 10; ++c) {
        fv[c]  = f1[(size_t)c*HW];
        h1v[c] = h1[(size_t)c*HW];
        h2v[c] = h2[(size_t)c*HW];
    }

    const size_t O1 = (size_t)3*BB*CC*HW;
    #pragma unroll
    for (int j = 0; j < 3; ++j) {
        float s = b_dmap[j];
        #pragma unroll
        for (int c = 0; c < 10; ++c) s = fmaf(w_dmap[j*30 + c],      fv[c],  s);
        #pragma unroll
        for (int c = 0; c < 10; ++c) s = fmaf(w_dmap[j*30 + 10 + c], h1v[c], s);
        #pragma unroll
        for (int c = 0; c < 10; ++c) s = fmaf(w_dmap[j*30 + 20 + c], h2v[c], s);
        out[O1 + ((size_t)b*3 + j)*HW + sp] = s;
    }

    // comp_map_u over parts 1..4
    float su = b_cau[0];
    #pragma unroll
    for (int i = 0; i < 4; ++i) {
        const float* p = p_nodes + (size_t)((1+i)*BB + b)*CC*HW + sp;
        #pragma unroll
        for (int c = 0; c < 10; ++c) su = fmaf(w_cau[i*10 + c], p[(size_t)c*HW], su);
    }
    const size_t O2 = O1 + (size_t)BB*3*HW;
    out[O2 + (size_t)b*HW + sp] = 1.f / (1.f + expf(-su));

    // comp_map_l over parts 5..6
    float sl = b_cal[0];
    #pragma unroll
    for (int i = 0; i < 2; ++i) {
        const float* p = p_nodes + (size_t)((5+i)*BB + b)*CC*HW + sp;
        #pragma unroll
        for (int c = 0; c < 10; ++c) sl = fmaf(w_cal[i*10 + c], p[(size_t)c*HW], sl);
    }
    const size_t O3 = O2 + (size_t)BB*HW;
    out[O3 + (size_t)b*HW + sp] = 1.f / (1.f + expf(-sl));

    // xh_new slot 0 = h_nodes[0]
    float* o0 = out + (size_t)b*CC*HW + sp;
    #pragma unroll
    for (int c = 0; c < 10; ++c) o0[(size_t)c*HW] = h0[(size_t)c*HW];
}

// ---------------------------------------------------------------------------
// Kernel B helpers
// ---------------------------------------------------------------------------
__device__ __forceinline__ void stage_tile(const float* __restrict__ plane,
                                           const float* __restrict__ smap,
                                           float* __restrict__ sTile,
                                           int y0, int x0, int tid)
{
    for (int e = tid; e < 10*324; e += 256) {
        int c  = e / 324;
        int r  = e - c*324;
        int yy = r / 18;
        int xx = r - yy*18;
        int gy = y0 + yy - 1, gx = x0 + xx - 1;
        float v = 0.f;
        if ((unsigned)gy < 192u && (unsigned)gx < 192u) {
            v = plane[(size_t)c*HW + gy*WD + gx];
            if (smap) v *= smap[r];
        }
        sTile[e] = v;
    }
}

// weights in LDS laid out sW[ci*108 + k*12 + o] (o contiguous, 16B aligned rows)
__device__ __forceinline__ void conv_acc(const float* __restrict__ sTile,
                                         const float* __restrict__ sW,
                                         int ty, int tx, float acc[10])
{
    #pragma unroll
    for (int c = 0; c < 10; ++c) {
        const float* t = sTile + c*324 + ty*18 + tx;
        float v[9];
        v[0]=t[0];  v[1]=t[1];  v[2]=t[2];
        v[3]=t[18]; v[4]=t[19]; v[5]=t[20];
        v[6]=t[36]; v[7]=t[37]; v[8]=t[38];
        const float* w = sW + c*108;
        #pragma unroll
        for (int k = 0; k < 9; ++k) {
            const float* wk = w + k*12;
            float vk = v[k];
            #pragma unroll
            for (int o = 0; o < 10; ++o) acc[o] = fmaf(vk, wk[o], acc[o]);
        }
    }
}

// ---------------------------------------------------------------------------
// Kernel B: one half (upper or lower). 16x16 output tile per block.
//  msg = relu(bn(conv([f1*att, h]))) + sum_j relu(bn(conv_h + conv(p_j*cm)))
//  then pointwise ConvGRU, writes xh slot.
// ---------------------------------------------------------------------------
__global__ __launch_bounds__(256) void half_kernel(
    const float* __restrict__ f1base,   // f_nodes[1]  [B][10][HW]
    const float* __restrict__ hbase,    // h1 or h2    [B][10][HW]
    const float* __restrict__ pbase,    // first part  [nparts][B][10][HW]
    int nparts,
    const float* __restrict__ dmap,     // [B][3][HW] raw decomp logits
    int attIdx,                         // 1 or 2
    const float* __restrict__ cmap,     // [B][HW] sigmoid comp map
    const float* __restrict__ w_dec,    // (10,20,3,3)
    const float* __restrict__ gD, const float* __restrict__ bD,
    const float* __restrict__ w_cmp,    // (10,20,3,3)
    const float* __restrict__ gC, const float* __restrict__ bC,
    const float* __restrict__ wg, const float* __restrict__ bg,
    const float* __restrict__ wc, const float* __restrict__ gG,
    const float* __restrict__ beG,
    float* __restrict__ outp)           // xh slot base [B][10][HW]
{
    __shared__ float sWd[20*108];
    __shared__ float sWc[20*108];
    __shared__ float sTile[10*324];
    __shared__ float sMap[324];
    __shared__ float sPar[302]; // 0 gD,10 bD,20 gC,30 bC,40 gG,50 beG,60 wg[40],100 bg[2],102 wc[200]

    const int tx = threadIdx.x, ty = threadIdx.y;
    const int tid = ty*16 + tx;
    const int b = blockIdx.z;
    const int x0 = blockIdx.x*16, y0 = blockIdx.y*16;

    // --- load + transpose weights: [o][ci][k] -> [ci][k][o] with padded strides
    for (int i = tid; i < 1800; i += 256) {
        int o = i / 180, r = i - o*180;
        int ci = r / 9,  k = r - ci*9;
        sWd[ci*108 + k*12 + o] = w_dec[i];
        sWc[ci*108 + k*12 + o] = w_cmp[i];
    }
    if (tid < 10) {
        sPar[tid]      = gD[tid];  sPar[10+tid] = bD[tid];
        sPar[20+tid]   = gC[tid];  sPar[30+tid] = bC[tid];
        sPar[40+tid]   = gG[tid];  sPar[50+tid] = beG[tid];
    }
    if (tid < 40) sPar[60+tid] = wg[tid];
    if (tid < 2)  sPar[100+tid] = bg[tid];
    if (tid >= 56 && tid < 256 && tid-56 < 200) sPar[102 + (tid-56)] = wc[tid-56];

    const float* fb = f1base + (size_t)b*CC*HW;
    const float* hb = hbase  + (size_t)b*CC*HW;

    // --- stage attention tile (softmax of dmap, pick attIdx channel)
    for (int r = tid; r < 324; r += 256) {
        int yy = r/18, xx = r - yy*18;
        int gy = y0 + yy - 1, gx = x0 + xx - 1;
        float a = 0.f;
        if ((unsigned)gy < 192u && (unsigned)gx < 192u) {
            const float* dmb = dmap + (size_t)b*3*HW + gy*WD + gx;
            float d0 = dmb[0], d1 = dmb[HW], d2 = dmb[2*HW];
            float m  = fmaxf(d0, fmaxf(d1, d2));
            float e0 = expf(d0-m), e1 = expf(d1-m), e2 = expf(d2-m);
            a = ((attIdx == 1) ? e1 : e2) / (e0 + e1 + e2);
        }
        sMap[r] = a;
    }
    __syncthreads();

    // --- d-term: conv(f1*att, Wdec[:, 0:10]) ...
    stage_tile(fb, sMap, sTile, y0, x0, tid);
    __syncthreads();
    float accD[10];
    #pragma unroll
    for (int o = 0; o < 10; ++o) accD[o] = 0.f;
    conv_acc(sTile, sWd, ty, tx, accD);
    __syncthreads();

    // --- ... + conv(h, Wdec[:, 10:20]); also shared conv(h, Wcmp[:, 0:10])
    stage_tile(hb, nullptr, sTile, y0, x0, tid);
    __syncthreads();
    float hc[10];
    #pragma unroll
    for (int c = 0; c < 10; ++c) hc[c] = sTile[c*324 + (ty+1)*18 + (tx+1)];
    conv_acc(sTile, sWd + 10*108, ty, tx, accD);
    float accH[10];
    #pragma unroll
    for (int o = 0; o < 10; ++o) accH[o] = 0.f;
    conv_acc(sTile, sWc, ty, tx, accH);
    __syncthreads();

    float msg[10];
    #pragma unroll
    for (int o = 0; o < 10; ++o) {
        float t = fmaf(sPar[o], accD[o], sPar[10+o]);
        msg[o] = fmaxf(t, 0.f);
    }

    // --- stage comp map tile
    for (int r = tid; r < 324; r += 256) {
        int yy = r/18, xx = r - yy*18;
        int gy = y0 + yy - 1, gx = x0 + xx - 1;
        float a = 0.f;
        if ((unsigned)gy < 192u && (unsigned)gx < 192u)
            a = cmap[(size_t)b*HW + gy*WD + gx];
        sMap[r] = a;
    }
    __syncthreads();

    // --- parts: msg += relu(bn(accH + conv(p_j*cm, Wcmp[:, 10:20])))
    for (int j = 0; j < nparts; ++j) {
        const float* pb = pbase + ((size_t)j*BB + b)*CC*HW;
        stage_tile(pb, sMap, sTile, y0, x0, tid);
        __syncthreads();
        float t[10];
        #pragma unroll
        for (int o = 0; o < 10; ++o) t[o] = accH[o];
        conv_acc(sTile, sWc + 10*108, ty, tx, t);
        #pragma unroll
        for (int o = 0; o < 10; ++o) {
            float v = fmaf(sPar[20+o], t[o], sPar[30+o]);
            msg[o] += fmaxf(v, 0.f);
        }
        __syncthreads();
    }

    // --- ConvGRU (all 1x1, pointwise)
    float g0 = sPar[100], g1 = sPar[101];
    #pragma unroll
    for (int c = 0; c < 10; ++c) {
        g0 = fmaf(sPar[60+c], msg[c], g0);
        g1 = fmaf(sPar[80+c], msg[c], g1);
    }
    #pragma unroll
    for (int c = 0; c < 10; ++c) {
        g0 = fmaf(sPar[70+c], hc[c], g0);
        g1 = fmaf(sPar[90+c], hc[c], g1);
    }
    float r = 1.f / (1.f + expf(-g0));
    float u = 1.f / (1.f + expf(-g1));

    float* op = outp + (size_t)b*CC*HW + (y0+ty)*WD + (x0+tx);
    #pragma unroll
    for (int o = 0; o < 10; ++o) {
        float s = 0.f;
        const float* wr = &sPar[102 + o*20];
        #pragma unroll
        for (int c = 0; c < 10; ++c) s = fmaf(wr[c], msg[c], s);
        #pragma unroll
        for (int c = 0; c < 10; ++c) s = fmaf(wr[10+c], r*hc[c], s);
        s = fmaf(sPar[40+o], s, sPar[50+o]);
        s = (s > 0.f) ? s : 0.01f*s;
        op[(size_t)o*HW] = (1.f - u)*hc[o] + u*s;
    }
}

// ---------------------------------------------------------------------------
extern "C" void kernel_launch(void* const* d_in, const int* in_sizes, int n_in,
                              void* d_out, int out_size, void* d_ws, size_t ws_size,
                              hipStream_t stream)
{
    const float* f_nodes = (const float*)d_in[0];
    const float* h_nodes = (const float*)d_in[1];
    const float* p_nodes = (const float*)d_in[2];
    // d_in[3] = xh (unused by reference)
    const float* w_dmap   = (const float*)d_in[4];
    const float* b_dmap   = (const float*)d_in[5];
    const float* w_decomp = (const float*)d_in[6];
    const float* g_decomp = (const float*)d_in[7];
    const float* be_decomp= (const float*)d_in[8];
    const float* w_cau    = (const float*)d_in[9];
    const float* b_cau    = (const float*)d_in[10];
    const float* w_cal    = (const float*)d_in[11];
    const float* b_cal    = (const float*)d_in[12];
    const float* w_cu     = (const float*)d_in[13];
    const float* g_cu     = (const float*)d_in[14];
    const float* be_cu    = (const float*)d_in[15];
    const float* w_cl     = (const float*)d_in[16];
    const float* g_cl     = (const float*)d_in[17];
    const float* be_cl    = (const float*)d_in[18];
    const float* wg_u     = (const float*)d_in[19];
    const float* bg_u     = (const float*)d_in[20];
    const float* wc_u     = (const float*)d_in[21];
    const float* g_u      = (const float*)d_in[22];
    const float* be_u     = (const float*)d_in[23];
    const float* wg_l     = (const float*)d_in[24];
    const float* bg_l     = (const float*)d_in[25];
    const float* wc_l     = (const float*)d_in[26];
    const float* g_l      = (const float*)d_in[27];
    const float* be_l     = (const float*)d_in[28];

    float* out = (float*)d_out;
    const size_t O1 = (size_t)3*BB*CC*HW;           // decomp_map
    const size_t O2 = O1 + (size_t)BB*3*HW;         // comp_map_u
    const size_t O3 = O2 + (size_t)BB*HW;           // comp_map_l

    // Kernel A: pointwise maps + h0 copy
    maps_kernel<<<dim3((BB*HW)/256), dim3(256), 0, stream>>>(
        f_nodes, h_nodes, p_nodes, w_dmap, b_dmap, w_cau, b_cau, w_cal, b_cal, out);

    dim3 grid(WD/16, WD/16, BB), blk(16, 16, 1);

    // Upper half: h1, parts 1..4, att channel 1
    half_kernel<<<grid, blk, 0, stream>>>(
        f_nodes + (size_t)1*BB*CC*HW,
        h_nodes + (size_t)1*BB*CC*HW,
        p_nodes + (size_t)1*BB*CC*HW, 4,
        out + O1, 1, out + O2,
        w_decomp, g_decomp, be_decomp,
        w_cu, g_cu, be_cu,
        wg_u, bg_u, wc_u, g_u, be_u,
        out + (size_t)1*BB*CC*HW);

    // Lower half: h2, parts 5..6, att channel 2
    half_kernel<<<grid, blk, 0, stream>>>(
        f_nodes + (size_t)1*BB*CC*HW,
        h_nodes + (size_t)2*BB*CC*HW,
        p_nodes + (size_t)5*BB*CC*HW, 2,
        out + O1, 2, out + O3,
        w_decomp, g_decomp, be_decomp,
        w_cl, g_cl, be_cl,
        wg_l, bg_l, wc_l, g_l, be_l,
        out + (size_t)2*BB*CC*HW);
}

// Round 2
// 371.754 us; speedup vs baseline: 1.3088x; 1.3088x over previous
//
#include <hip/hip_runtime.h>

#define HW 36864      // 192*192
#define WD 192
#define BB 8
#define CC 10

typedef __attribute__((ext_vector_type(8))) short short8;
typedef __attribute__((ext_vector_type(4))) float f32x4;

__device__ __forceinline__ short f2bf(float v) {
    unsigned u = __float_as_uint(v);
    unsigned r = (u + 0x7fffu + ((u >> 16) & 1u)) >> 16;   // RNE
    return (short)r;
}

// ---------------------------------------------------------------------------
// Kernel A: all 1x1 pointwise maps + h0 copy (fp32, unchanged from R1).
// ---------------------------------------------------------------------------
__global__ __launch_bounds__(256) void maps_kernel(
    const float* __restrict__ f_nodes, const float* __restrict__ h_nodes,
    const float* __restrict__ p_nodes,
    const float* __restrict__ w_dmap, const float* __restrict__ b_dmap,
    const float* __restrict__ w_cau, const float* __restrict__ b_cau,
    const float* __restrict__ w_cal, const float* __restrict__ b_cal,
    float* __restrict__ out)
{
    int px = blockIdx.x * 256 + threadIdx.x;
    int b  = px / HW;
    int sp = px - b * HW;

    const float* f1 = f_nodes + (size_t)(1*BB + b)*CC*HW + sp;
    const float* h0 = h_nodes + (size_t)(0*BB + b)*CC*HW + sp;
    const float* h1 = h_nodes + (size_t)(1*BB + b)*CC*HW + sp;
    const float* h2 = h_nodes + (size_t)(2*BB + b)*CC*HW + sp;

    float fv[10], h1v[10], h2v[10];
    #pragma unroll
    for (int c = 0; c < 10; ++c) {
        fv[c]  = f1[(size_t)c*HW];
        h1v[c] = h1[(size_t)c*HW];
        h2v[c] = h2[(size_t)c*HW];
    }

    const size_t O1 = (size_t)3*BB*CC*HW;
    #pragma unroll
    for (int j = 0; j < 3; ++j) {
        float s = b_dmap[j];
        #pragma unroll
        for (int c = 0; c < 10; ++c) s = fmaf(w_dmap[j*30 + c],      fv[c],  s);
        #pragma unroll
        for (int c = 0; c < 10; ++c) s = fmaf(w_dmap[j*30 + 10 + c], h1v[c], s);
        #pragma unroll
        for (int c = 0; c < 10; ++c) s = fmaf(w_dmap[j*30 + 20 + c], h2v[c], s);
        out[O1 + ((size_t)b*3 + j)*HW + sp] = s;
    }

    float su = b_cau[0];
    #pragma unroll
    for (int i = 0; i < 4; ++i) {
        const float* p = p_nodes + (size_t)((1+i)*BB + b)*CC*HW + sp;
        #pragma unroll
        for (int c = 0; c < 10; ++c) su = fmaf(w_cau[i*10 + c], p[(size_t)c*HW], su);
    }
    const size_t O2 = O1 + (size_t)BB*3*HW;
    out[O2 + (size_t)b*HW + sp] = 1.f / (1.f + expf(-su));

    float sl = b_cal[0];
    #pragma unroll
    for (int i = 0; i < 2; ++i) {
        const float* p = p_nodes + (size_t)((5+i)*BB + b)*CC*HW + sp;
        #pragma unroll
        for (int c = 0; c < 10; ++c) sl = fmaf(w_cal[i*10 + c], p[(size_t)c*HW], sl);
    }
    const size_t O3 = O2 + (size_t)BB*HW;
    out[O3 + (size_t)b*HW + sp] = 1.f / (1.f + expf(-sl));

    float* o0 = out + (size_t)b*CC*HW + sp;
    #pragma unroll
    for (int c = 0; c < 10; ++c) o0[(size_t)c*HW] = h0[(size_t)c*HW];
}

// ---------------------------------------------------------------------------
// Kernel B: one half, bf16-MFMA implicit GEMM.
// Tile 16x16 px/block, 256 thr = 4 waves, wave w owns rows 4w..4w+3.
// LDS tile: [19*18 px][24 bf16] (c0..9 = h, c10..19 = partner, c20..23 = 0,
// row 18 zeroed for the K-pad kpos=9). K = kpos*24 + c, 7 chunks of 32.
// A-frag and B-frag are each ONE ds_read_b128 per lane per MFMA.
// ---------------------------------------------------------------------------
__global__ __launch_bounds__(256) void half_kernel(
    const float* __restrict__ f1base,
    const float* __restrict__ hbase,
    const float* __restrict__ pbase, int nparts,
    const float* __restrict__ dmap, int attIdx,
    const float* __restrict__ cmap,
    const float* __restrict__ w_dec,
    const float* __restrict__ gD, const float* __restrict__ bD,
    const float* __restrict__ w_cmp,
    const float* __restrict__ gC, const float* __restrict__ bC,
    const float* __restrict__ wg, const float* __restrict__ bg,
    const float* __restrict__ wc, const float* __restrict__ gG,
    const float* __restrict__ beG,
    float* __restrict__ outp)
{
    __shared__ short sT[342*24];      // 19 rows x 18 cols x 24ch bf16 = 16416 B
    __shared__ short sWb[2*16*232];   // [conv][n16][k232] bf16 = 14848 B
    __shared__ float sMap[324];
    __shared__ float sMsg[256*12];    // 12288 B
    __shared__ float sPar[302];

    const int tid  = threadIdx.x;
    const int lane = tid & 63;
    const int w    = tid >> 6;
    const int g    = lane >> 4;
    const int n    = lane & 15;       // = out-channel for B/D, = pixel-x for A
    const int b    = blockIdx.z;
    const int x0   = blockIdx.x*16, y0 = blockIdx.y*16;

    // ---- zero bf16 pads (junk bf16 could be NaN; NaN*0 = NaN)
    {
        int* z = (int*)sT;
        for (int i = tid; i < 342*24/2; i += 256) z[i] = 0;
        int* z2 = (int*)sWb;
        for (int i = tid; i < 2*16*232/2; i += 256) z2[i] = 0;
    }
    __syncthreads();

    // ---- weights: transpose (o,ci,kp) -> Wb[n=o][kp*24 + slot], bf16
    for (int i = tid; i < 1800; i += 256) {
        int o = i/180, r = i - o*180;
        int ci = r/9, kp = r - ci*9;
        // decomp source concat = [f(0..9), h(10..19)]; our slots = [h, f]
        int slot_d = (ci >= 10) ? (ci - 10) : (ci + 10);
        sWb[o*232 + kp*24 + slot_d]      = f2bf(w_dec[i]);
        // comp source concat = [h(0..9), p(10..19)] -> slots match directly
        sWb[16*232 + o*232 + kp*24 + ci] = f2bf(w_cmp[i]);
    }
    if (tid < 10) {
        sPar[tid]    = gD[tid];  sPar[10+tid] = bD[tid];
        sPar[20+tid] = gC[tid];  sPar[30+tid] = bC[tid];
        sPar[40+tid] = gG[tid];  sPar[50+tid] = beG[tid];
    }
    if (tid < 40) sPar[60+tid]  = wg[tid];
    if (tid < 2)  sPar[100+tid] = bg[tid];
    if (tid >= 56 && tid < 256) sPar[102+(tid-56)] = (tid-56 < 200) ? wc[tid-56] : 0.f;

    // ---- attention map (softmax of dmap, channel attIdx) over halo tile
    for (int r = tid; r < 324; r += 256) {
        int yy = r/18, xx = r - yy*18;
        int gy = y0 + yy - 1, gx = x0 + xx - 1;
        float a = 0.f;
        if ((unsigned)gy < 192u && (unsigned)gx < 192u) {
            const float* dmb = dmap + (size_t)b*3*HW + gy*WD + gx;
            float d0 = dmb[0], d1 = dmb[HW], d2 = dmb[2*HW];
            float mx = fmaxf(d0, fmaxf(d1, d2));
            float e0 = expf(d0-mx), e1 = expf(d1-mx), e2 = expf(d2-mx);
            a = ((attIdx == 1) ? e1 : e2) / (e0 + e1 + e2);
        }
        sMap[r] = a;
    }
    __syncthreads();   // sWb, sPar, sMap(att) ready; sT zeroed

    // ---- stage h (slots 0..9) + f*att (slots 10..19), bf16
    const float* fb = f1base + (size_t)b*CC*HW;
    const float* hb = hbase  + (size_t)b*CC*HW;
    for (int e = tid; e < 3240; e += 256) {
        int c = e/324, r = e - c*324;
        int yy = r/18, xx = r - yy*18;
        int gy = y0 + yy - 1, gx = x0 + xx - 1;
        float vh = 0.f, vf = 0.f;
        if ((unsigned)gy < 192u && (unsigned)gx < 192u) {
            int off = gy*WD + gx;
            vh = hb[(size_t)c*HW + off];
            vf = fb[(size_t)c*HW + off] * sMap[r];
        }
        sT[r*24 + c]      = f2bf(vh);
        sT[r*24 + 10 + c] = f2bf(vf);
    }
    __syncthreads();   // tile ready

    // ---- per-lane A-fragment offsets (short units), one per K-chunk
    int aoff[7];
    #pragma unroll
    for (int t = 0; t < 7; ++t) {
        int ks = 32*t + 8*g;            // k_start for this lane's group
        int kp = ks/24;                 // kernel position 0..9 (9 = pad row)
        int c8 = ks - kp*24;            // 0,8,16
        int ky = kp/3, kx = kp - ky*3;
        aoff[t] = ((ky*18) + kx + n)*24 + c8;
    }
    const int wbase = w*4*432;          // wave's row-block base (4 rows * 18*24)

    // ---- decomp pass: conv([h | f*att], Wdec) -> msg = relu(bn(.))
    f32x4 msgf[4];
    {
        short8 bfr[7];
        #pragma unroll
        for (int t = 0; t < 7; ++t)
            bfr[t] = *(const short8*)(sWb + n*232 + 32*t + 8*g);
        f32x4 acc[4];
        #pragma unroll
        for (int mt = 0; mt < 4; ++mt) acc[mt] = (f32x4){0.f,0.f,0.f,0.f};
        #pragma unroll
        for (int t = 0; t < 7; ++t) {
            #pragma unroll
            for (int mt = 0; mt < 4; ++mt) {
                short8 a = *(const short8*)(sT + wbase + mt*432 + aoff[t]);
                acc[mt] = __builtin_amdgcn_mfma_f32_16x16x32_bf16(a, bfr[t], acc[mt], 0, 0, 0);
            }
        }
        int np = (n < 10) ? n : 9;
        float gDv = sPar[np], bDv = sPar[10+np];
        #pragma unroll
        for (int mt = 0; mt < 4; ++mt) {
            #pragma unroll
            for (int j = 0; j < 4; ++j)
                msgf[mt][j] = fmaxf(fmaf(gDv, acc[mt][j], bDv), 0.f);
        }
    }

    // ---- overwrite sMap with comp map (no readers during this phase)
    for (int r = tid; r < 324; r += 256) {
        int yy = r/18, xx = r - yy*18;
        int gy = y0 + yy - 1, gx = x0 + xx - 1;
        float a = 0.f;
        if ((unsigned)gy < 192u && (unsigned)gx < 192u)
            a = cmap[(size_t)b*HW + gy*WD + gx];
        sMap[r] = a;
    }

    // ---- preload comp B-frags (shared across all parts)
    short8 bfc[7];
    #pragma unroll
    for (int t = 0; t < 7; ++t)
        bfc[t] = *(const short8*)(sWb + 16*232 + n*232 + 32*t + 8*g);

    int np = (n < 10) ? n : 9;
    float gCv = sPar[20+np], bCv = sPar[30+np];
    __syncthreads();   // cmap ready; decomp done reading partner slots

    // ---- part passes: msg += relu(bn(conv([h | p_j*cm], Wcmp)))
    for (int j = 0; j < nparts; ++j) {
        const float* pb = pbase + ((size_t)j*BB + b)*CC*HW;
        for (int e = tid; e < 3240; e += 256) {
            int c = e/324, r = e - c*324;
            int yy = r/18, xx = r - yy*18;
            int gy = y0 + yy - 1, gx = x0 + xx - 1;
            float v = 0.f;
            if ((unsigned)gy < 192u && (unsigned)gx < 192u)
                v = pb[(size_t)c*HW + gy*WD + gx] * sMap[r];
            sT[r*24 + 10 + c] = f2bf(v);
        }
        __syncthreads();

        f32x4 acc[4];
        #pragma unroll
        for (int mt = 0; mt < 4; ++mt) acc[mt] = (f32x4){0.f,0.f,0.f,0.f};
        #pragma unroll
        for (int t = 0; t < 7; ++t) {
            #pragma unroll
            for (int mt = 0; mt < 4; ++mt) {
                short8 a = *(const short8*)(sT + wbase + mt*432 + aoff[t]);
                acc[mt] = __builtin_amdgcn_mfma_f32_16x16x32_bf16(a, bfc[t], acc[mt], 0, 0, 0);
            }
        }
        #pragma unroll
        for (int mt = 0; mt < 4; ++mt) {
            #pragma unroll
            for (int jj = 0; jj < 4; ++jj)
                msgf[mt][jj] += fmaxf(fmaf(gCv, acc[mt][jj], bCv), 0.f);
        }
        __syncthreads();
    }

    // ---- transpose msg (D-layout: lane n holds ch n, pixels x=4g+reg) -> sMsg
    if (n < 10) {
        #pragma unroll
        for (int mt = 0; mt < 4; ++mt) {
            #pragma unroll
            for (int r2 = 0; r2 < 4; ++r2) {
                int q = (4*w + mt)*16 + 4*g + r2;
                sMsg[q*12 + n] = msgf[mt][r2];
            }
        }
    }
    __syncthreads();

    // ---- fp32 pointwise ConvGRU epilogue, one pixel per thread
    {
        int q = tid;
        int row = q >> 4, xx = q & 15;
        int gy = y0 + row, gx = x0 + xx;

        float msg[10], hc[10];
        #pragma unroll
        for (int c = 0; c < 10; ++c) msg[c] = sMsg[q*12 + c];
        const float* hp = hb + gy*WD + gx;
        #pragma unroll
        for (int c = 0; c < 10; ++c) hc[c] = hp[(size_t)c*HW];

        float g0 = sPar[100], g1 = sPar[101];
        #pragma unroll
        for (int c = 0; c < 10; ++c) {
            g0 = fmaf(sPar[60+c], msg[c], g0);
            g1 = fmaf(sPar[80+c], msg[c], g1);
        }
        #pragma unroll
        for (int c = 0; c < 10; ++c) {
            g0 = fmaf(sPar[70+c], hc[c], g0);
            g1 = fmaf(sPar[90+c], hc[c], g1);
        }
        float r = 1.f / (1.f + expf(-g0));
        float u = 1.f / (1.f + expf(-g1));

        float* op = outp + (size_t)b*CC*HW + gy*WD + gx;
        #pragma unroll
        for (int o = 0; o < 10; ++o) {
            float s = 0.f;
            const float* wr = &sPar[102 + o*20];
            #pragma unroll
            for (int c = 0; c < 10; ++c) s = fmaf(wr[c], msg[c], s);
            #pragma unroll
            for (int c = 0; c < 10; ++c) s = fmaf(wr[10+c], r*hc[c], s);
            s = fmaf(sPar[40+o], s, sPar[50+o]);
            s = (s > 0.f) ? s : 0.01f*s;
            op[(size_t)o*HW] = (1.f - u)*hc[o] + u*s;
        }
    }
}

// ---------------------------------------------------------------------------
extern "C" void kernel_launch(void* const* d_in, const int* in_sizes, int n_in,
                              void* d_out, int out_size, void* d_ws, size_t ws_size,
                              hipStream_t stream)
{
    const float* f_nodes = (const float*)d_in[0];
    const float* h_nodes = (const float*)d_in[1];
    const float* p_nodes = (const float*)d_in[2];
    const float* w_dmap   = (const float*)d_in[4];
    const float* b_dmap   = (const float*)d_in[5];
    const float* w_decomp = (const float*)d_in[6];
    const float* g_decomp = (const float*)d_in[7];
    const float* be_decomp= (const float*)d_in[8];
    const float* w_cau    = (const float*)d_in[9];
    const float* b_cau    = (const float*)d_in[10];
    const float* w_cal    = (const float*)d_in[11];
    const float* b_cal    = (const float*)d_in[12];
    const float* w_cu     = (const float*)d_in[13];
    const float* g_cu     = (const float*)d_in[14];
    const float* be_cu    = (const float*)d_in[15];
    const float* w_cl     = (const float*)d_in[16];
    const float* g_cl     = (const float*)d_in[17];
    const float* be_cl    = (const float*)d_in[18];
    const float* wg_u     = (const float*)d_in[19];
    const float* bg_u     = (const float*)d_in[20];
    const float* wc_u     = (const float*)d_in[21];
    const float* g_u      = (const float*)d_in[22];
    const float* be_u     = (const float*)d_in[23];
    const float* wg_l     = (const float*)d_in[24];
    const float* bg_l     = (const float*)d_in[25];
    const float* wc_l     = (const float*)d_in[26];
    const float* g_l      = (const float*)d_in[27];
    const float* be_l     = (const float*)d_in[28];

    float* out = (float*)d_out;
    const size_t O1 = (size_t)3*BB*CC*HW;           // decomp_map
    const size_t O2 = O1 + (size_t)BB*3*HW;         // comp_map_u
    const size_t O3 = O2 + (size_t)BB*HW;           // comp_map_l

    maps_kernel<<<dim3((BB*HW)/256), dim3(256), 0, stream>>>(
        f_nodes, h_nodes, p_nodes, w_dmap, b_dmap, w_cau, b_cau, w_cal, b_cal, out);

    dim3 grid(WD/16, WD/16, BB), blk(256, 1, 1);

    half_kernel<<<grid, blk, 0, stream>>>(
        f_nodes + (size_t)1*BB*CC*HW,
        h_nodes + (size_t)1*BB*CC*HW,
        p_nodes + (size_t)1*BB*CC*HW, 4,
        out + O1, 1, out + O2,
        w_decomp, g_decomp, be_decomp,
        w_cu, g_cu, be_cu,
        wg_u, bg_u, wc_u, g_u, be_u,
        out + (size_t)1*BB*CC*HW);

    half_kernel<<<grid, blk, 0, stream>>>(
        f_nodes + (size_t)1*BB*CC*HW,
        h_nodes + (size_t)2*BB*CC*HW,
        p_nodes + (size_t)5*BB*CC*HW, 2,
        out + O1, 2, out + O3,
        w_decomp, g_decomp, be_decomp,
        w_cl, g_cl, be_cl,
        wg_l, bg_l, wc_l, g_l, be_l,
        out + (size_t)2*BB*CC*HW);
}

// Round 3
// 317.317 us; speedup vs baseline: 1.5333x; 1.1716x over previous
//
#include <hip/hip_runtime.h>

#define HW 36864      // 192*192
#define WD 192
#define BB 8
#define CC 10
#define PW 194                          // padded width (1px zero border)
#define PB ((size_t)(PW*PW*16))         // shorts per (array, b) = 602176
#define PA ((size_t)BB*PB)              // shorts per array
// ws requirement: 10 arrays * PA shorts * 2 B = 96,348,160 bytes

typedef __attribute__((ext_vector_type(8))) short short8;
typedef __attribute__((ext_vector_type(4))) float f32x4;

__device__ __forceinline__ short f2bf(float v) {
    unsigned u = __float_as_uint(v);
    unsigned r = (u + 0x7fffu + ((u >> 16) & 1u)) >> 16;   // RNE
    return (short)r;
}
__device__ __forceinline__ float b2f(short s) {
    return __uint_as_float(((unsigned)(unsigned short)s) << 16);
}

#define ASYNC16(gp, lp) __builtin_amdgcn_global_load_lds( \
    (const __attribute__((address_space(1))) void*)(gp),  \
    (__attribute__((address_space(3))) void*)(lp), 16, 0, 0)

// ---------------------------------------------------------------------------
// prep: pointwise maps (dmap/softmax, comp maps), h0 copy, and bf16 c16-packed
// padded conv-input arrays into ws:
//   arr0=h1, arr1=h2, arr2=f*att1, arr3=f*att2, arr4..7=p1..4*cmU, arr8..9=p5..6*cmL
// ---------------------------------------------------------------------------
__device__ __forceinline__ void store16(short* d, const float* v, float s) {
    short8 lo, hi;
    #pragma unroll
    for (int i = 0; i < 8; ++i) lo[i] = f2bf(v[i]*s);
    hi = (short8){f2bf(v[8]*s), f2bf(v[9]*s), 0,0,0,0,0,0};
    *(short8*)d = lo;
    *(short8*)(d+8) = hi;
}

__global__ __launch_bounds__(256) void prep_kernel(
    const float* __restrict__ f_nodes, const float* __restrict__ h_nodes,
    const float* __restrict__ p_nodes,
    const float* __restrict__ w_dmap, const float* __restrict__ b_dmap,
    const float* __restrict__ w_cau, const float* __restrict__ b_cau,
    const float* __restrict__ w_cal, const float* __restrict__ b_cal,
    float* __restrict__ out, short* __restrict__ ws)
{
    int t = blockIdx.x*256 + threadIdx.x;
    if (t >= BB*PW*PW) return;
    int b  = t / (PW*PW);
    int pp = t - b*(PW*PW);
    int py = pp / PW, px = pp - py*PW;
    short* wb = ws + (size_t)b*PB + (size_t)pp*16;

    if (py == 0 || py == PW-1 || px == 0 || px == PW-1) {
        short8 z = (short8){0,0,0,0,0,0,0,0};
        #pragma unroll
        for (int a = 0; a < 10; ++a) {
            *(short8*)(wb + (size_t)a*PA)     = z;
            *(short8*)(wb + (size_t)a*PA + 8) = z;
        }
        return;
    }
    int sp = (py-1)*WD + (px-1);

    const float* f1 = f_nodes + ((size_t)(BB   + b))*CC*HW + sp;
    const float* h0 = h_nodes + ((size_t)(       b))*CC*HW + sp;
    const float* h1 = h_nodes + ((size_t)(BB   + b))*CC*HW + sp;
    const float* h2 = h_nodes + ((size_t)(2*BB + b))*CC*HW + sp;

    float fv[10], av[10], bv[10];
    #pragma unroll
    for (int c = 0; c < 10; ++c) {
        fv[c] = f1[(size_t)c*HW];
        av[c] = h1[(size_t)c*HW];
        bv[c] = h2[(size_t)c*HW];
    }

    const size_t O1 = (size_t)3*BB*CC*HW;
    const size_t O2 = O1 + (size_t)BB*3*HW;
    const size_t O3 = O2 + (size_t)BB*HW;

    float dm[3];
    #pragma unroll
    for (int j = 0; j < 3; ++j) {
        float s = b_dmap[j];
        #pragma unroll
        for (int c = 0; c < 10; ++c) s = fmaf(w_dmap[j*30 + c],      fv[c], s);
        #pragma unroll
        for (int c = 0; c < 10; ++c) s = fmaf(w_dmap[j*30 + 10 + c], av[c], s);
        #pragma unroll
        for (int c = 0; c < 10; ++c) s = fmaf(w_dmap[j*30 + 20 + c], bv[c], s);
        dm[j] = s;
        out[O1 + ((size_t)b*3 + j)*HW + sp] = s;
    }
    float mx = fmaxf(dm[0], fmaxf(dm[1], dm[2]));
    float e0 = expf(dm[0]-mx), e1 = expf(dm[1]-mx), e2 = expf(dm[2]-mx);
    float inv = 1.f / (e0 + e1 + e2);
    float a1 = e1*inv, a2 = e2*inv;

    store16(wb + 0*PA, av, 1.f);   // h1
    store16(wb + 1*PA, bv, 1.f);   // h2
    store16(wb + 2*PA, fv, a1);    // f*att1
    store16(wb + 3*PA, fv, a2);    // f*att2

    // h0 copy to out slot 0
    float* o0 = out + (size_t)b*CC*HW + sp;
    #pragma unroll
    for (int c = 0; c < 10; ++c) o0[(size_t)c*HW] = h0[(size_t)c*HW];

    // upper parts
    {
        float pv[4][10];
        float su = b_cau[0];
        #pragma unroll
        for (int i = 0; i < 4; ++i) {
            const float* p = p_nodes + ((size_t)((1+i)*BB + b))*CC*HW + sp;
            #pragma unroll
            for (int c = 0; c < 10; ++c) pv[i][c] = p[(size_t)c*HW];
            #pragma unroll
            for (int c = 0; c < 10; ++c) su = fmaf(w_cau[i*10 + c], pv[i][c], su);
        }
        float cmU = 1.f / (1.f + expf(-su));
        out[O2 + (size_t)b*HW + sp] = cmU;
        #pragma unroll
        for (int i = 0; i < 4; ++i) store16(wb + (size_t)(4+i)*PA, pv[i], cmU);
    }
    // lower parts
    {
        float qv[2][10];
        float sl = b_cal[0];
        #pragma unroll
        for (int i = 0; i < 2; ++i) {
            const float* p = p_nodes + ((size_t)((5+i)*BB + b))*CC*HW + sp;
            #pragma unroll
            for (int c = 0; c < 10; ++c) qv[i][c] = p[(size_t)c*HW];
            #pragma unroll
            for (int c = 0; c < 10; ++c) sl = fmaf(w_cal[i*10 + c], qv[i][c], sl);
        }
        float cmL = 1.f / (1.f + expf(-sl));
        out[O3 + (size_t)b*HW + sp] = cmL;
        #pragma unroll
        for (int i = 0; i < 2; ++i) store16(wb + (size_t)(8+i)*PA, qv[i], cmL);
    }
}

// ---------------------------------------------------------------------------
// half_kernel: both halves (z 0..7 upper, 8..15 lower). 16x16 px tile/block.
// Tiles DMA'd straight into LDS (18 rows x 18 px x 16ch bf16 = 648 x16B chunks,
// buffer padded to 768 chunks so 3 full 256-thread DMA rounds never spill).
// ---------------------------------------------------------------------------
__device__ __forceinline__ void dma_tile(short* lds, const short* g,
                                         int tid, int y0, int x0)
{
    #pragma unroll
    for (int r = 0; r < 3; ++r) {
        int idx = r*256 + tid;
        int row = idx / 36;               // 36 chunks (576 B) per tile row
        int col = idx - row*36;
        size_t go = (idx < 648) ? (((size_t)(y0+row)*PW + x0)*16 + (size_t)col*8)
                                : (size_t)0;
        ASYNC16(g + go, lds + (size_t)idx*8);
    }
}

__global__ __launch_bounds__(256) void half_kernel(
    const short* __restrict__ ws,
    const float* __restrict__ w_dec, const float* __restrict__ gD, const float* __restrict__ bD,
    const float* __restrict__ w_cu, const float* __restrict__ gCu, const float* __restrict__ bCu,
    const float* __restrict__ w_cl, const float* __restrict__ gCl, const float* __restrict__ bCl,
    const float* __restrict__ wg_u, const float* __restrict__ bg_u, const float* __restrict__ wc_u,
    const float* __restrict__ g_u, const float* __restrict__ be_u,
    const float* __restrict__ wg_l, const float* __restrict__ bg_l, const float* __restrict__ wc_l,
    const float* __restrict__ g_l, const float* __restrict__ be_l,
    float* __restrict__ out)
{
    __shared__ __align__(16) short sTh[6144];   // 768*8 shorts = 12288 B
    __shared__ __align__(16) short sTp0[6144];
    __shared__ __align__(16) short sTp1[6144];
    __shared__ __align__(16) short sWb[4*2688]; // 4 sets x 16 n x 168 k (pad)
    __shared__ float sMsg[256*13];
    __shared__ float sPar[302];

    const int tid  = threadIdx.x;
    const int lane = tid & 63;
    const int w    = tid >> 6;
    const int g    = lane >> 4;
    const int n    = lane & 15;
    const int half = blockIdx.z >> 3;
    const int b    = blockIdx.z & 7;
    const int x0   = blockIdx.x*16, y0 = blockIdx.y*16;

    const float* w_cmp = half ? w_cl : w_cu;
    const float* gC  = half ? gCl  : gCu;
    const float* bC  = half ? bCl  : bCu;
    const float* wg  = half ? wg_l : wg_u;
    const float* bg  = half ? bg_l : bg_u;
    const float* wc  = half ? wc_l : wc_u;
    const float* gG  = half ? g_l  : g_u;
    const float* beG = half ? be_l : be_u;
    const int nparts = half ? 2 : 4;

    const short* hArr  = ws + (size_t)half*PA     + (size_t)b*PB;
    const short* fArr  = ws + (size_t)(2+half)*PA + (size_t)b*PB;
    const short* pArr0 = ws + (size_t)(4+half*4)*PA + (size_t)b*PB;

    // zero weight LDS (pad slots must be 0), then kick off the three DMAs
    for (int i = tid; i < 4*2688/2; i += 256) ((int*)sWb)[i] = 0;
    dma_tile(sTh,  hArr,  tid, y0, x0);
    dma_tile(sTp0, fArr,  tid, y0, x0);
    dma_tile(sTp1, pArr0, tid, y0, x0);
    __syncthreads();

    // fill weights (set0=Wd_f, set1=Wd_h, set2=Wc_h, set3=Wc_p) + params
    for (int i = tid; i < 1800; i += 256) {
        int o = i/180, r = i - o*180, ci = r/9, kp = r - ci*9;
        int c  = (ci < 10) ? ci : ci - 10;
        int s2 = (ci < 10) ? 0 : 1;
        sWb[s2*2688     + o*168 + kp*16 + c] = f2bf(w_dec[i]);
        sWb[(2+s2)*2688 + o*168 + kp*16 + c] = f2bf(w_cmp[i]);
    }
    if (tid < 10) {
        sPar[tid]    = gD[tid];  sPar[10+tid] = bD[tid];
        sPar[20+tid] = gC[tid];  sPar[30+tid] = bC[tid];
        sPar[40+tid] = gG[tid];  sPar[50+tid] = beG[tid];
    }
    if (tid < 40) sPar[60+tid]  = wg[tid];
    if (tid < 2)  sPar[100+tid] = bg[tid];
    if (tid >= 56 && tid < 256) sPar[102+(tid-56)] = (tid-56 < 200) ? wc[tid-56] : 0.f;
    __syncthreads();

    // per-lane A-fragment offsets; K = kpos*16 + c, kpos 9 = dummy (0 weights)
    int aoff[5];
    #pragma unroll
    for (int t5 = 0; t5 < 5; ++t5) {
        int k  = 32*t5 + 8*g;
        int kp = k >> 4;
        int c8 = k & 15;
        if (kp < 9) { int ky = kp/3, kx = kp - ky*3; aoff[t5] = (ky*18 + kx + n)*16 + c8; }
        else        aoff[t5] = 0;
    }
    const int wbase = w*4*288;      // 288 shorts per tile row

    // B-fragments
    short8 bF[5], bH[5], bCh[5], bCp[5];
    #pragma unroll
    for (int t5 = 0; t5 < 5; ++t5) {
        int ko = 32*t5 + 8*g;
        bF[t5]  = *(const short8*)(sWb + 0*2688 + n*168 + ko);
        bH[t5]  = *(const short8*)(sWb + 1*2688 + n*168 + ko);
        bCh[t5] = *(const short8*)(sWb + 2*2688 + n*168 + ko);
        bCp[t5] = *(const short8*)(sWb + 3*2688 + n*168 + ko);
    }

    // decomp: conv(f*att, Wd_f) + conv(h, Wd_h); shared accH = conv(h, Wc_h)
    f32x4 accD[4], accH[4];
    #pragma unroll
    for (int mt = 0; mt < 4; ++mt) { accD[mt] = (f32x4){0,0,0,0}; accH[mt] = (f32x4){0,0,0,0}; }
    #pragma unroll
    for (int t5 = 0; t5 < 5; ++t5) {
        #pragma unroll
        for (int mt = 0; mt < 4; ++mt) {
            short8 a = *(const short8*)(sTp0 + wbase + mt*288 + aoff[t5]);
            accD[mt] = __builtin_amdgcn_mfma_f32_16x16x32_bf16(a, bF[t5], accD[mt], 0,0,0);
        }
    }
    #pragma unroll
    for (int t5 = 0; t5 < 5; ++t5) {
        #pragma unroll
        for (int mt = 0; mt < 4; ++mt) {
            short8 a = *(const short8*)(sTh + wbase + mt*288 + aoff[t5]);
            accD[mt] = __builtin_amdgcn_mfma_f32_16x16x32_bf16(a, bH[t5],  accD[mt], 0,0,0);
            accH[mt] = __builtin_amdgcn_mfma_f32_16x16x32_bf16(a, bCh[t5], accH[mt], 0,0,0);
        }
    }
    const int np = (n < 10) ? n : 9;
    const float gDv = sPar[np],    bDv = sPar[10+np];
    const float gCv = sPar[20+np], bCv = sPar[30+np];
    f32x4 msgf[4];
    #pragma unroll
    for (int mt = 0; mt < 4; ++mt)
        #pragma unroll
        for (int j = 0; j < 4; ++j)
            msgf[mt][j] = fmaxf(fmaf(gDv, accD[mt][j], bDv), 0.f);
    __syncthreads();   // all waves done reading sTp0 (f*att)

    // parts, double-buffered: p0 in sTp1; prefetch p_{j+1} into the freed buf
    for (int j = 0; j < nparts; ++j) {
        if (j+1 < nparts)
            dma_tile((j&1) ? sTp1 : sTp0, pArr0 + (size_t)(j+1)*PA, tid, y0, x0);
        const short* cur = (j&1) ? sTp0 : sTp1;
        f32x4 acc[4];
        #pragma unroll
        for (int mt = 0; mt < 4; ++mt) acc[mt] = (f32x4){0,0,0,0};
        #pragma unroll
        for (int t5 = 0; t5 < 5; ++t5) {
            #pragma unroll
            for (int mt = 0; mt < 4; ++mt) {
                short8 a = *(const short8*)(cur + wbase + mt*288 + aoff[t5]);
                acc[mt] = __builtin_amdgcn_mfma_f32_16x16x32_bf16(a, bCp[t5], acc[mt], 0,0,0);
            }
        }
        #pragma unroll
        for (int mt = 0; mt < 4; ++mt)
            #pragma unroll
            for (int jj = 0; jj < 4; ++jj)
                msgf[mt][jj] += fmaxf(fmaf(gCv, accH[mt][jj] + acc[mt][jj], bCv), 0.f);
        __syncthreads();   // cur fully consumed; prefetch drained
    }

    // transpose msg to [pixel][ch]
    if (n < 10) {
        #pragma unroll
        for (int mt = 0; mt < 4; ++mt)
            #pragma unroll
            for (int r2 = 0; r2 < 4; ++r2)
                sMsg[((4*w + mt)*16 + 4*g + r2)*13 + n] = msgf[mt][r2];
    }
    __syncthreads();

    // pointwise ConvGRU epilogue (fp32), one pixel/thread; h from bf16 tile
    {
        int row = tid >> 4, xx = tid & 15;
        int gy = y0 + row, gx = x0 + xx;
        float msg[10], hc[10];
        #pragma unroll
        for (int c = 0; c < 10; ++c) msg[c] = sMsg[tid*13 + c];
        #pragma unroll
        for (int c = 0; c < 10; ++c) hc[c] = b2f(sTh[((row+1)*18 + (xx+1))*16 + c]);

        float g0 = sPar[100], g1 = sPar[101];
        #pragma unroll
        for (int c = 0; c < 10; ++c) {
            g0 = fmaf(sPar[60+c], msg[c], g0);
            g1 = fmaf(sPar[80+c], msg[c], g1);
        }
        #pragma unroll
        for (int c = 0; c < 10; ++c) {
            g0 = fmaf(sPar[70+c], hc[c], g0);
            g1 = fmaf(sPar[90+c], hc[c], g1);
        }
        float r = 1.f / (1.f + expf(-g0));
        float u = 1.f / (1.f + expf(-g1));

        float* op = out + (size_t)(1+half)*BB*CC*HW + (size_t)b*CC*HW + gy*WD + gx;
        #pragma unroll
        for (int o = 0; o < 10; ++o) {
            float s = 0.f;
            const float* wr = &sPar[102 + o*20];
            #pragma unroll
            for (int c = 0; c < 10; ++c) s = fmaf(wr[c], msg[c], s);
            #pragma unroll
            for (int c = 0; c < 10; ++c) s = fmaf(wr[10+c], r*hc[c], s);
            s = fmaf(sPar[40+o], s, sPar[50+o]);
            s = (s > 0.f) ? s : 0.01f*s;
            op[(size_t)o*HW] = (1.f - u)*hc[o] + u*s;
        }
    }
}

// ---------------------------------------------------------------------------
extern "C" void kernel_launch(void* const* d_in, const int* in_sizes, int n_in,
                              void* d_out, int out_size, void* d_ws, size_t ws_size,
                              hipStream_t stream)
{
    const float* f_nodes = (const float*)d_in[0];
    const float* h_nodes = (const float*)d_in[1];
    const float* p_nodes = (const float*)d_in[2];
    const float* w_dmap   = (const float*)d_in[4];
    const float* b_dmap   = (const float*)d_in[5];
    const float* w_decomp = (const float*)d_in[6];
    const float* g_decomp = (const float*)d_in[7];
    const float* be_decomp= (const float*)d_in[8];
    const float* w_cau    = (const float*)d_in[9];
    const float* b_cau    = (const float*)d_in[10];
    const float* w_cal    = (const float*)d_in[11];
    const float* b_cal    = (const float*)d_in[12];
    const float* w_cu     = (const float*)d_in[13];
    const float* g_cu     = (const float*)d_in[14];
    const float* be_cu    = (const float*)d_in[15];
    const float* w_cl     = (const float*)d_in[16];
    const float* g_cl     = (const float*)d_in[17];
    const float* be_cl    = (const float*)d_in[18];
    const float* wg_u     = (const float*)d_in[19];
    const float* bg_u     = (const float*)d_in[20];
    const float* wc_u     = (const float*)d_in[21];
    const float* g_u      = (const float*)d_in[22];
    const float* be_u     = (const float*)d_in[23];
    const float* wg_l     = (const float*)d_in[24];
    const float* bg_l     = (const float*)d_in[25];
    const float* wc_l     = (const float*)d_in[26];
    const float* g_l      = (const float*)d_in[27];
    const float* be_l     = (const float*)d_in[28];

    float* out = (float*)d_out;
    short* ws  = (short*)d_ws;

    prep_kernel<<<dim3((BB*PW*PW + 255)/256), dim3(256), 0, stream>>>(
        f_nodes, h_nodes, p_nodes, w_dmap, b_dmap,
        w_cau, b_cau, w_cal, b_cal, out, ws);

    half_kernel<<<dim3(WD/16, WD/16, 16), dim3(256), 0, stream>>>(
        ws, w_decomp, g_decomp, be_decomp,
        w_cu, g_cu, be_cu, w_cl, g_cl, be_cl,
        wg_u, bg_u, wc_u, g_u, be_u,
        wg_l, bg_l, wc_l, g_l, be_l,
        out);
}